// Round 6
// baseline (9197.301 us; speedup 1.0000x reference)
//
#include <hip/hip_runtime.h>

// Persistent 4-layer LSTM, MFMA split-bf16. H=256, B=32, SEQ=1024, L=4.
//
// Grid: 128 WGs x 256 thr. WG (l, w): layer l (bx>>5), owns units [w*8, w*8+8)
// x 4 gates = 32 gate-rows x all 32 batches. GEMM/step: D[m=32 batch][n=32 rows]
// = v[32][512] * Wcat^T, K = 512 (x(256) || h(256)).
// Wave q: mh=q&1 (batch half), nh=q>>1 (row half) -> one 16x16 C-tile.
// Weights resident in VGPRs as bf16 hi/lo (3-term split: hh + hl + lh).
//
// Sync design (round 6 — ZERO-POISONED self-validating data):
//   * h workspace slots 1..SEQ are hipMemsetAsync'd to 0 before the kernel
//     (slot 0 = fp32 h0 preserved). Producers tag every packed h dword with
//     LSB=1 (perturbs the RESIDUAL bf16 mantissa LSB, <= 2^-15 |h|).
//     Consumers load fragments as 64-bit relaxed AGENT atomics and retry
//     until every dword has LSB==1.
//   * ROUNDS 3-5 ROOT CAUSE: with RANDOM stale data, a PARTIALLY-written slot
//     passes the LSB check with p=1/2 per stale dword (random fp32 LSB) ->
//     garbage lo-bf16 (random exponent, incl. Inf/NaN) fed to MFMA -> NaN.
//     Zero-poisoning makes stale LSB == 0 ALWAYS: per-dword validation is
//     exact, no ordering/atomicity/probability assumptions. p(false pass)=0.
//   * No flags, no store drains: h publish = relaxed agent atomic store,
//     fire-and-forget; the consumer's validation IS the sync.
//   * Order per step: x-half (below layer, normally ready) -> x-half MFMA ->
//     spin on own-layer h (the recurrence edge) -> h-half MFMA. Shortens the
//     post-h-ready critical path and halves peak fragment liveness.
//   * Raw s_barrier (lgkmcnt-only where LDS requires) so outstanding h stores
//     are never drained on the critical path.

#define HID  256
#define BAT  32
#define SEQL 1024
#define NLAY 4
#define NE   (HID*BAT)       // 8192
#define WGPL 32              // WGs per layer
#define GSTR 36              // lds gate-exchange row stride (floats)

typedef __attribute__((ext_vector_type(8))) short bf16x8;
typedef __attribute__((ext_vector_type(4))) float f32x4;
typedef unsigned long long u64;

union U8 { bf16x8 v; unsigned short s[8]; unsigned u[4]; };

__device__ __forceinline__ unsigned short bf16_rne(float f) {
    unsigned u = __float_as_uint(f);
    u += 0x7FFFu + ((u >> 16) & 1u);
    return (unsigned short)(u >> 16);
}
__device__ __forceinline__ float bf16_to_f(unsigned short h) {
    return __uint_as_float(((unsigned)h) << 16);
}
__device__ __forceinline__ unsigned pack_hl(float f) {
    unsigned short hi = bf16_rne(f);
    unsigned short lo = bf16_rne(f - bf16_to_f(hi));
    return (((unsigned)hi) << 16) | lo;
}

__device__ __forceinline__ float sigm(float x)  { return 1.0f / (1.0f + __expf(-x)); }
__device__ __forceinline__ float tanhx(float x) { return 1.0f - 2.0f / (__expf(2.0f * x) + 1.0f); }

// One MFMA k-slice: 8 packed dwords (4 u64) -> hi/lo fragments -> 3 MFMAs.
__device__ __forceinline__ void mfma_step(u64 q0, u64 q1, u64 q2, u64 q3,
                                          bf16x8 bh, bf16x8 bl,
                                          f32x4& a0, f32x4& a1, f32x4& a2) {
    unsigned d0 = (unsigned)q0, d1 = (unsigned)(q0 >> 32);
    unsigned d2 = (unsigned)q1, d3 = (unsigned)(q1 >> 32);
    unsigned d4 = (unsigned)q2, d5 = (unsigned)(q2 >> 32);
    unsigned d6 = (unsigned)q3, d7 = (unsigned)(q3 >> 32);
    U8 ahi, alo;
    ahi.u[0] = __builtin_amdgcn_perm(d1, d0, 0x07060302u);
    ahi.u[1] = __builtin_amdgcn_perm(d3, d2, 0x07060302u);
    ahi.u[2] = __builtin_amdgcn_perm(d5, d4, 0x07060302u);
    ahi.u[3] = __builtin_amdgcn_perm(d7, d6, 0x07060302u);
    alo.u[0] = __builtin_amdgcn_perm(d1, d0, 0x05040100u);
    alo.u[1] = __builtin_amdgcn_perm(d3, d2, 0x05040100u);
    alo.u[2] = __builtin_amdgcn_perm(d5, d4, 0x05040100u);
    alo.u[3] = __builtin_amdgcn_perm(d7, d6, 0x05040100u);
    a0 = __builtin_amdgcn_mfma_f32_16x16x32_bf16(ahi.v, bh, a0, 0, 0, 0);
    a1 = __builtin_amdgcn_mfma_f32_16x16x32_bf16(ahi.v, bl, a1, 0, 0, 0);
    a2 = __builtin_amdgcn_mfma_f32_16x16x32_bf16(alo.v, bh, a2, 0, 0, 0);
}

// In-place pack of layer-0 input x: fp32 -> (bf16hi<<16)|bf16lo, elementwise.
__global__ __launch_bounds__(256) void pack_x(unsigned* xp) {
    int i = (blockIdx.x * 256 + threadIdx.x) * 4;   // SEQ*NE = 8192*1024 covered exactly
    float4 f = *(const float4*)((const float*)xp + i);
    uint4 u;
    u.x = pack_hl(f.x); u.y = pack_hl(f.y);
    u.z = pack_hl(f.z); u.w = pack_hl(f.w);
    *(uint4*)(xp + i) = u;
}

__global__ __launch_bounds__(256, 1)
void lstm_mfma(unsigned* __restrict__ hslab,       // h_data as dwords (slots s>=1 = hbuf, ZEROED)
               const float* __restrict__ c_data,
               const float* __restrict__ W,
               const float* __restrict__ R,
               const float* __restrict__ bias,
               const unsigned* __restrict__ xpack,  // x_data slab 0, packed
               float* __restrict__ out)
{
    __shared__ float ldsg[32 * GSTR];

    const int tid  = threadIdx.x;
    const int bx   = blockIdx.x;
    const int l    = bx >> 5;
    const int w    = bx & 31;

    const int wv   = tid >> 6;
    const int lane = tid & 63;
    const int mh   = wv & 1;          // batch half
    const int nh   = wv >> 1;         // row half
    const int ln15 = lane & 15;
    const int kq   = lane >> 4;       // 0..3 k-block

    const int n_loc = nh * 16 + ln15;             // local gate-row 0..31
    const int gate  = n_loc >> 3;
    const int uu    = n_loc & 7;
    const int grow  = gate * HID + w * 8 + uu;    // global gate-row in [0,1024)
    const int bg    = mh * 16 + ln15;             // batch for A-frags

    // ---- resident weight fragments: Bhi/Blo[s], s=0..15 (K=512) ----
    bf16x8 Bhi[16], Blo[16];
    {
        const float* Wl = W + (size_t)l * 4 * HID * HID;
        const float* Rl = R + (size_t)l * 4 * HID * HID;
        #pragma unroll
        for (int s = 0; s < 16; ++s) {
            int k0 = s * 32 + kq * 8;
            const float* src = (k0 < HID) ? (Wl + (size_t)grow * HID + k0)
                                          : (Rl + (size_t)grow * HID + (k0 - HID));
            float4 f0 = *(const float4*)src;
            float4 f1 = *(const float4*)(src + 4);
            float ff[8] = {f0.x, f0.y, f0.z, f0.w, f1.x, f1.y, f1.z, f1.w};
            U8 hi, lo;
            #pragma unroll
            for (int j = 0; j < 8; ++j) {
                hi.s[j] = bf16_rne(ff[j]);
                lo.s[j] = bf16_rne(ff[j] - bf16_to_f(hi.s[j]));
            }
            Bhi[s] = hi.v; Blo[s] = lo.v;
        }
    }

    const float bias_n = bias[l * 4 * HID + grow];

    // c-state owner: thread (uu2, b2)
    const int uu2 = tid >> 5;
    const int b2  = tid & 31;
    float cst = c_data[(size_t)l * (SEQL + 1) * NE + b2 * HID + w * 8 + uu2];

    unsigned* hbuf = hslab;  // slot (l,s) at ((l*(SEQL+1))+s)*NE
    const float* h0f = (const float*)hslab + (size_t)l * (SEQL + 1) * NE;

    for (int t = 0; t < SEQL; ++t) {
        const unsigned* xsrc = (l == 0)
            ? (xpack + (size_t)t * NE)
            : (hbuf + ((size_t)(l - 1) * (SEQL + 1) + (t + 1)) * NE);
        const unsigned* hsrc = hbuf + ((size_t)l * (SEQL + 1) + t) * NE;

        f32x4 acc0 = {bias_n, bias_n, bias_n, bias_n};
        f32x4 acc1 = {0.f, 0.f, 0.f, 0.f};
        f32x4 acc2 = {0.f, 0.f, 0.f, 0.f};

        // ================= x-half (k = 0..255) =================
        {
            u64 xq[32];
            if (l == 0) {
                // static pre-packed input: plain loads
                #pragma unroll
                for (int s = 0; s < 8; ++s) {
                    const u64* p = (const u64*)(xsrc + bg * HID + s * 32 + kq * 8);
                    #pragma unroll
                    for (int j = 0; j < 4; ++j) xq[4 * s + j] = p[j];
                }
            } else {
                // below-layer h: validated atomic loads (stale == 0 -> LSB 0)
                int tries = 0;
                for (;;) {
                    unsigned m = 0xFFFFFFFFu;
                    #pragma unroll
                    for (int s = 0; s < 8; ++s) {
                        const u64* p = (const u64*)(xsrc + bg * HID + s * 32 + kq * 8);
                        #pragma unroll
                        for (int j = 0; j < 4; ++j) {
                            u64 v = __hip_atomic_load(p + j, __ATOMIC_RELAXED,
                                                      __HIP_MEMORY_SCOPE_AGENT);
                            xq[4 * s + j] = v;
                            m &= (unsigned)v & (unsigned)(v >> 32);
                        }
                    }
                    if (__all((m & 1u) != 0u)) break;
                    if (++tries > 4) __builtin_amdgcn_s_sleep(1);  // fill-phase backoff
                }
            }
            #pragma unroll
            for (int s = 0; s < 8; ++s)
                mfma_step(xq[4 * s], xq[4 * s + 1], xq[4 * s + 2], xq[4 * s + 3],
                          Bhi[s], Blo[s], acc0, acc1, acc2);
        }

        // ================= h-half (k = 256..511) — the recurrence edge =======
        {
            u64 hq[32];
            if (t == 0) {
                // h0 is fp32 in h_data slot 0: plain loads + pack
                #pragma unroll
                for (int s = 0; s < 8; ++s) {
                    const float* hp = h0f + bg * HID + s * 32 + kq * 8;
                    #pragma unroll
                    for (int j = 0; j < 4; ++j) {
                        float2 f = *(const float2*)(hp + 2 * j);
                        hq[4 * s + j] = (u64)pack_hl(f.x)
                                      | ((u64)pack_hl(f.y) << 32);
                    }
                }
            } else {
                int tries = 0;
                for (;;) {
                    unsigned m = 0xFFFFFFFFu;
                    #pragma unroll
                    for (int s = 0; s < 8; ++s) {
                        const u64* p = (const u64*)(hsrc + bg * HID + s * 32 + kq * 8);
                        #pragma unroll
                        for (int j = 0; j < 4; ++j) {
                            u64 v = __hip_atomic_load(p + j, __ATOMIC_RELAXED,
                                                      __HIP_MEMORY_SCOPE_AGENT);
                            hq[4 * s + j] = v;
                            m &= (unsigned)v & (unsigned)(v >> 32);
                        }
                    }
                    if (__all((m & 1u) != 0u)) break;
                    if (++tries > 16) __builtin_amdgcn_s_sleep(1);  // backoff if far behind
                }
            }
            #pragma unroll
            for (int s = 0; s < 8; ++s)
                mfma_step(hq[4 * s], hq[4 * s + 1], hq[4 * s + 2], hq[4 * s + 3],
                          Bhi[8 + s], Blo[8 + s], acc0, acc1, acc2);
        }

        f32x4 cc = acc0 + acc1;
        cc = cc + acc2;

        // ---- exchange gates via LDS: ldsg[n][m], D: m=(lane>>4)*4+r, n=lane&15 ----
        *(f32x4*)&ldsg[n_loc * GSTR + mh * 16 + kq * 4] = cc;
        // raw barrier: LDS writes visible (lgkmcnt), but do NOT drain vmcnt
        // (outstanding h stores stay in flight)
        asm volatile("s_waitcnt lgkmcnt(0)\n\ts_barrier" ::: "memory");

        // ---- elementwise update by cell owner (uu2, b2) ----
        float hv;
        {
            float gi = ldsg[(0 * 8 + uu2) * GSTR + b2];
            float gf = ldsg[(1 * 8 + uu2) * GSTR + b2];
            float gg = ldsg[(2 * 8 + uu2) * GSTR + b2];
            float go = ldsg[(3 * 8 + uu2) * GSTR + b2];
            float iv = sigm(gi), fv = sigm(gf), gv = tanhx(gg), ov = sigm(go);
            cst = fv * cst + iv * gv;
            hv = ov * tanhx(cst);
            unsigned dw = pack_hl(hv) | 1u;       // LSB tag: "this dword is live"
            unsigned* dst = hbuf + ((size_t)l * (SEQL + 1) + (t + 1)) * NE
                          + b2 * HID + w * 8 + uu2;
            __hip_atomic_store(dst, dw, __ATOMIC_RELAXED,
                               __HIP_MEMORY_SCOPE_AGENT);  // fire-and-forget
        }
        if (l == NLAY - 1)
            out[(size_t)t * NE + b2 * HID + w * 8 + uu2] = hv;

        // raw barrier: protect ldsg reuse next step (gate reads already
        // consumed via dataflow); no vmcnt/lgkm drain needed
        asm volatile("s_barrier" ::: "memory");
    }
}

extern "C" void kernel_launch(void* const* d_in, const int* in_sizes, int n_in,
                              void* d_out, int out_size, void* d_ws, size_t ws_size,
                              hipStream_t stream) {
    unsigned*    h_data = (unsigned*)d_in[0];
    unsigned*    x_data = (unsigned*)d_in[1];
    float*       c_data = (float*)d_in[2];
    const float* W      = (const float*)d_in[3];
    const float* R      = (const float*)d_in[4];
    const float* bias   = (const float*)d_in[5];
    float* out = (float*)d_out;

    // Zero-poison h slots 1..SEQ of every layer (slot 0 = fp32 h0 preserved).
    // Stale dword == 0 (LSB 0) makes per-dword LSB validation EXACT.
    // 4 x 32 MB ~ 20 us at HBM BW; stream-ordered before the persistent kernel.
    for (int l = 0; l < NLAY; ++l) {
        unsigned* slot1 = h_data + ((size_t)l * (SEQL + 1) + 1) * NE;
        hipMemsetAsync(slot1, 0, (size_t)SEQL * NE * sizeof(unsigned), stream);
    }

    // pack layer-0 x in place (SEQ*NE elements = 8192 blocks * 256 thr * 4)
    pack_x<<<dim3(8192), dim3(256), 0, stream>>>(x_data);

    lstm_mfma<<<dim3(NLAY * WGPL), dim3(256), 0, stream>>>(
        h_data, c_data, W, R, bias, x_data, out);
}